// Round 16
// baseline (529.070 us; speedup 1.0000x reference)
//
#include <hip/hip_runtime.h>

// B=4, T=8, H=W=16, C=F=256, gates 4F=1024. K = 9*256 = 2304.
// Round 16: rec v11 — 32x64 tile, 512 blocks (2/CU), 4 waves (2x2),
// wave 16m x 32n (2 nf per wave): A ds_read:MFMA ratio halves (2:4),
// A redundancy 4x->2x, LDS/body 80->48KB per CU. 6-buffer ring (4KB each),
// B in regs 3-deep (8 v8h/set), uniform vmcnt(10), xg+cbuf prefetch.
// conv_big/BN/wprep/gates0 unchanged from r15.
#define HW      256
#define COUT    1024
#define TSTEPS  8
#define BN_EPS  1e-3f
#define KTOT    2304

typedef unsigned short u16;
typedef unsigned int   u32;
typedef __attribute__((ext_vector_type(8))) _Float16 v8h;  // 8 x fp16
typedef __attribute__((ext_vector_type(4))) float v4f;

__device__ __forceinline__ u16 f2h(float x) {
    _Float16 h = (_Float16)x; return *(u16*)&h;
}
__device__ __forceinline__ float h2f(u16 u) {
    _Float16 h = *(_Float16*)&u; return (float)h;
}
__device__ __forceinline__ float hsig(float x) {
    return fminf(fmaxf(0.2f * x + 0.5f, 0.f), 1.f);
}

typedef __attribute__((address_space(1))) const unsigned int gas_u32;
typedef __attribute__((address_space(3))) unsigned int las_u32;
__device__ __forceinline__ void gl16(const void* g, void* l) {
    __builtin_amdgcn_global_load_lds((gas_u32*)g, (las_u32*)l, 16, 0, 0);
}

// ---------------------------------------------------------------------------
// Big input conv (r13/r15 version): M=8192, N'=1024, BM=BN=128, BK=64,
// 4 waves, single-barrier depth-2 pipeline, slot-swizzled LDS, 2 blk/CU.
// ---------------------------------------------------------------------------
__global__ __launch_bounds__(256, 2) void conv_big_k(
    const u16* __restrict__ apad,     // (32,18,18,256) fp16 zero-padded
    const u16* __restrict__ wT,       // (1024 n', 2304) fp16
    const float* __restrict__ bias,   // (1024) original n order
    u16* __restrict__ out)            // (8192, 1024) fp16, n' order
{
    constexpr int KQ = 36;
    __shared__ u16 lds[2 * 16384];

    const int bid = blockIdx.x;
    const int xcd = bid & 7, idx = bid >> 3;
    const int by = (xcd >> 1) * 2 + (idx & 1);
    const int bx = (xcd & 1) * 32 + (idx >> 1);
    const int m0 = bx * 128, n0 = by * 128;
    const int tid = threadIdx.x, lane = tid & 63, w = tid >> 6;
    const int wr = w >> 1, wc = w & 1;
    const int lr = lane >> 3;
    const int g  = (lane & 7) ^ lr;
    const int fr = lane & 15, kc = lane >> 4;

    const char* a_src[4];
    #pragma unroll
    for (int i = 0; i < 4; ++i) {
        int m = m0 + w * 32 + i * 8 + lr;
        int img = m >> 8, pix = m & 255, yy = pix >> 4, xx = pix & 15;
        a_src[i] = (const char*)apad + ((((long)img * 18 + yy) * 18 + xx) * 256 + g * 8) * 2;
    }
    const char* b_src[4];
    #pragma unroll
    for (int i = 0; i < 4; ++i) {
        int n = n0 + w * 32 + i * 8 + lr;
        b_src[i] = (const char*)wT + ((long)n * KTOT + g * 8) * 2;
    }

    int aro[4][2], bro[4][2];
    #pragma unroll
    for (int mi = 0; mi < 4; ++mi) {
        int rl = wr * 64 + mi * 16 + fr;
        #pragma unroll
        for (int ks = 0; ks < 2; ++ks)
            aro[mi][ks] = rl * 128 + ((((ks << 2) | kc) ^ (fr & 7)) << 4);
    }
    #pragma unroll
    for (int ni = 0; ni < 4; ++ni) {
        int nr = wc * 64 + ni * 16 + fr;
        #pragma unroll
        for (int ks = 0; ks < 2; ++ks)
            bro[ni][ks] = 16384 + nr * 128 + ((((ks << 2) | kc) ^ (fr & 7)) << 4);
    }

    v4f acc[4][4];
    #pragma unroll
    for (int mi = 0; mi < 4; ++mi)
        #pragma unroll
        for (int ni = 0; ni < 4; ++ni) acc[mi][ni] = (v4f)0.f;

#define STAGE_B(J) { int j_ = (J); int dxy = j_ >> 2, c64 = j_ & 3;           \
    int dy = (dxy * 11) >> 5; int dx = dxy - dy * 3;                          \
    int aoff = ((dy * 18 + dx) * 256 + c64 * 64) * 2; int boff = j_ * 128;    \
    char* base = (char*)lds + (j_ & 1) * 32768;                               \
    _Pragma("unroll") for (int i = 0; i < 4; ++i)                             \
        gl16(a_src[i] + aoff, base + (w * 32 + i * 8) * 128);                 \
    _Pragma("unroll") for (int i = 0; i < 4; ++i)                             \
        gl16(b_src[i] + boff, base + 16384 + (w * 32 + i * 8) * 128); }

#define COMPUTE_B(J) { const char* base = (const char*)lds + ((J) & 1) * 32768; \
    v8h af[4][2], bf[4][2];                                                   \
    _Pragma("unroll") for (int mi = 0; mi < 4; ++mi)                          \
        _Pragma("unroll") for (int ks = 0; ks < 2; ++ks)                      \
            af[mi][ks] = *(const v8h*)(base + aro[mi][ks]);                   \
    _Pragma("unroll") for (int ni = 0; ni < 4; ++ni)                          \
        _Pragma("unroll") for (int ks = 0; ks < 2; ++ks)                      \
            bf[ni][ks] = *(const v8h*)(base + bro[ni][ks]);                   \
    __builtin_amdgcn_s_setprio(1);                                            \
    _Pragma("unroll") for (int ks = 0; ks < 2; ++ks)                          \
    _Pragma("unroll") for (int mi = 0; mi < 4; ++mi)                          \
    _Pragma("unroll") for (int ni = 0; ni < 4; ++ni)                          \
        acc[mi][ni] = __builtin_amdgcn_mfma_f32_16x16x32_f16(af[mi][ks], bf[ni][ks], acc[mi][ni], 0, 0, 0); \
    __builtin_amdgcn_s_setprio(0); }

    STAGE_B(0);
    for (int kq = 0; kq < KQ - 1; ++kq) {
        asm volatile("s_waitcnt vmcnt(0)" ::: "memory");
        __builtin_amdgcn_s_barrier();
        __builtin_amdgcn_sched_barrier(0);
        STAGE_B(kq + 1);
        COMPUTE_B(kq);
    }
    asm volatile("s_waitcnt vmcnt(0)" ::: "memory");
    __builtin_amdgcn_s_barrier();
    __builtin_amdgcn_sched_barrier(0);
    COMPUTE_B(KQ - 1);
#undef STAGE_B
#undef COMPUTE_B

    #pragma unroll
    for (int mi = 0; mi < 4; ++mi) {
        #pragma unroll
        for (int ni = 0; ni < 4; ++ni) {
            int mrow = m0 + wr * 64 + mi * 16 + ((lane >> 4) << 2);
            int ncol = n0 + wc * 64 + ni * 16 + fr;
            float b0 = bias[(ncol & 3) * 256 + (ncol >> 2)];
            #pragma unroll
            for (int r = 0; r < 4; ++r)
                out[(long)(mrow + r) * COUT + ncol] = f2h(acc[mi][ni][r] + b0);
        }
    }
}

// ---------------------------------------------------------------------------
// Recurrent conv + fused LSTM cell, v11: 32x64 tile, 512 blocks (2/CU),
// 4 waves (2wr x 2wc), wave 16m x 32n (2 nf). BK=128 bodies, 18 barriers,
// 6-buffer 4KB LDS ring, B regs 3-deep (8 v8h/set), uniform vmcnt(10),
// xg + cbuf prefetch issued first, hs fp16.
// ---------------------------------------------------------------------------
__global__ __launch_bounds__(256, 2) void rec_fused_k(
    const u16* __restrict__ ph_in,    // (4,18,18,256) fp16  h_{t-1}
    const u16* __restrict__ wTf,      // frag-packed Wh: (64 nf, 72 k32, 512)
    const u16* __restrict__ xg,       // (8192, 1024) fp16, n' order (incl bias)
    float* __restrict__ cbuf,         // (4,256,256)
    u16* __restrict__ hs16,           // (8192,256) fp16
    u16* __restrict__ ph_out,         // (4,18,18,256) fp16  h_t
    int t)
{
    __shared__ u16 lds[6 * 2048];     // 6 bufs x 4KB (A only), 24KB

    const int bid = blockIdx.x;       // 512: by-pairs per XCD (bijective)
    const int by = (bid & 7) * 2 + ((bid >> 3) & 1);   // 0..15
    const int bx = bid >> 4;                           // 0..31
    const int m0 = bx * 32, n0 = by * 64;
    const int tid = threadIdx.x, lane = tid & 63, w = tid >> 6;
    const int wr = w >> 1, wc = w & 1;
    const int fr = lane & 15, kc = lane >> 4;

    // epilogue coordinates (fixed) — xg + cbuf prefetch issued FIRST (4 VMEM)
    const int erow = m0 + wr * 16 + ((lane >> 4) << 2) + (lane & 3);
    const int eimg = erow >> 8, epix = erow & 255;
    const long xrow = ((long)(eimg * TSTEPS + t) * HW + epix);
    int f4[2]; long cidx[2];
    uint2 xb_pre[2];
    float c_pre[2];
    #pragma unroll
    for (int ni = 0; ni < 2; ++ni) {
        f4[ni] = n0 + wc * 32 + ni * 16 + (lane & 12);
        cidx[ni] = (long)erow * 256 + (f4[ni] >> 2);
        xb_pre[ni] = *(const uint2*)&xg[xrow * COUT + f4[ni]];
        c_pre[ni]  = cbuf[cidx[ni]];
    }

    // A staging: wave w stages rows w*8 .. w*8+7 (1KB = one gl16 per wave)
    const char* a_src;
    {
        int rt = w * 8 + (lane >> 3);
        int gg = (lane & 7) ^ (lane >> 3);   // inverse swizzle on SOURCE granule
        int m = m0 + rt;
        int img = m >> 8, pix = m & 255, yy = pix >> 4, xx = pix & 15;
        a_src = (const char*)ph_in + ((((long)img * 18 + yy) * 18 + xx) * 256 + gg * 8) * 2;
    }
    // B fragment bases: wave covers nf = by*4 + wc*2 + {0,1}
    const char* b_base0 = (const char*)wTf + ((long)(by * 4 + wc * 2 + 0) * 72) * 1024 + lane * 16;
    const char* b_base1 = b_base0 + 72 * 1024;

    // A frag read offsets (swizzled slot), rows wr*16 + fr
    int aro[2];
    #pragma unroll
    for (int ks = 0; ks < 2; ++ks)
        aro[ks] = (wr * 16 + fr) * 128 + ((((ks << 2) | kc) ^ (fr & 7)) << 4);

    v4f acc0 = (v4f)0.f, acc1 = (v4f)0.f;

// stage K64 chunk J into 4KB buffer BUF (one gl16 per wave)
#define STAGE_A(J, BUF) { int j_ = (J); int dxy = j_ >> 2, c64 = j_ & 3;      \
    int dy = (dxy * 11) >> 5; int dx = dxy - dy * 3;                          \
    int aoff = ((dy * 18 + dx) * 256 + c64 * 64) * 2;                         \
    gl16(a_src + aoff, (char*)lds + (BUF) * 4096 + w * 1024); }

// load K64 chunk J's B frags: R0=nf0ks0 R1=nf0ks1 R2=nf1ks0 R3=nf1ks1
#define LDCH(J, R0, R1, R2, R3) {                                             \
    R0 = *(const v8h*)(b_base0 + (2 * (J)) * 1024);                           \
    R1 = *(const v8h*)(b_base0 + (2 * (J) + 1) * 1024);                       \
    R2 = *(const v8h*)(b_base1 + (2 * (J)) * 1024);                           \
    R3 = *(const v8h*)(b_base1 + (2 * (J) + 1) * 1024); }

// compute one K64 chunk from buffer BUF (2 A reads, 4 MFMA)
#define CKQ(BUF, R0, R1, R2, R3) {                                            \
    const char* base_ = (const char*)lds + (BUF) * 4096;                      \
    v8h af0_ = *(const v8h*)(base_ + aro[0]);                                 \
    v8h af1_ = *(const v8h*)(base_ + aro[1]);                                 \
    __builtin_amdgcn_s_setprio(1);                                            \
    acc0 = __builtin_amdgcn_mfma_f32_16x16x32_f16(af0_, R0, acc0, 0, 0, 0);   \
    acc1 = __builtin_amdgcn_mfma_f32_16x16x32_f16(af0_, R2, acc1, 0, 0, 0);   \
    acc0 = __builtin_amdgcn_mfma_f32_16x16x32_f16(af1_, R1, acc0, 0, 0, 0);   \
    acc1 = __builtin_amdgcn_mfma_f32_16x16x32_f16(af1_, R3, acc1, 0, 0, 0);   \
    __builtin_amdgcn_s_setprio(0); }

// body J2: compute chunks 2J2,2J2+1 from bufs BC,BC+1; load+stage chunks
// 2J2+4,2J2+5 into (LA..),(LB..) and bufs BS,BS+1. 10 VMEM ops per body.
#define BODY2(J2, BC, BS, A0,A1,A2,A3, B0,B1,B2,B3, LA0,LA1,LA2,LA3, LB0,LB1,LB2,LB3) { \
    int q0_ = 2 * (J2);                                                       \
    asm volatile("s_waitcnt vmcnt(10)" ::: "memory");                         \
    __builtin_amdgcn_s_barrier();                                             \
    __builtin_amdgcn_sched_barrier(0);                                        \
    LDCH(q0_ + 4, LA0, LA1, LA2, LA3);                                        \
    LDCH(q0_ + 5, LB0, LB1, LB2, LB3);                                        \
    STAGE_A(q0_ + 4, BS); STAGE_A(q0_ + 5, (BS) + 1);                         \
    CKQ(BC,       A0, A1, A2, A3);                                            \
    CKQ((BC) + 1, B0, B1, B2, B3); }

    v8h Pa0,Pa1,Pa2,Pa3, Pb0,Pb1,Pb2,Pb3;
    v8h Qa0,Qa1,Qa2,Qa3, Qb0,Qb1,Qb2,Qb3;
    v8h Ra0,Ra1,Ra2,Ra3, Rb0,Rb1,Rb2,Rb3;
    // prologue: body0 (chunks 0,1 -> bufs 0,1), body1 (chunks 2,3 -> bufs 2,3)
    LDCH(0, Pa0,Pa1,Pa2,Pa3); LDCH(1, Pb0,Pb1,Pb2,Pb3);
    STAGE_A(0, 0); STAGE_A(1, 1);
    LDCH(2, Qa0,Qa1,Qa2,Qa3); LDCH(3, Qb0,Qb1,Qb2,Qb3);
    STAGE_A(2, 2); STAGE_A(3, 3);

    for (int j = 0; j < 5; ++j) {        // bodies 0..14
        BODY2(3 * j,     0, 4, Pa0,Pa1,Pa2,Pa3, Pb0,Pb1,Pb2,Pb3,
                               Ra0,Ra1,Ra2,Ra3, Rb0,Rb1,Rb2,Rb3);
        BODY2(3 * j + 1, 2, 0, Qa0,Qa1,Qa2,Qa3, Qb0,Qb1,Qb2,Qb3,
                               Pa0,Pa1,Pa2,Pa3, Pb0,Pb1,Pb2,Pb3);
        BODY2(3 * j + 2, 4, 2, Ra0,Ra1,Ra2,Ra3, Rb0,Rb1,Rb2,Rb3,
                               Qa0,Qa1,Qa2,Qa3, Qb0,Qb1,Qb2,Qb3);
    }
    // body 15 (chunks 30,31 from bufs 0,1; stages chunks 34,35 into bufs 4,5)
    BODY2(15, 0, 4, Pa0,Pa1,Pa2,Pa3, Pb0,Pb1,Pb2,Pb3,
                    Ra0,Ra1,Ra2,Ra3, Rb0,Rb1,Rb2,Rb3);
    // body 16 (chunks 32,33 from bufs 2,3; no issue)
    asm volatile("s_waitcnt vmcnt(10)" ::: "memory");
    __builtin_amdgcn_s_barrier();
    __builtin_amdgcn_sched_barrier(0);
    CKQ(2, Qa0,Qa1,Qa2,Qa3);
    CKQ(3, Qb0,Qb1,Qb2,Qb3);
    // body 17 (chunks 34,35 from bufs 4,5; no issue)
    asm volatile("s_waitcnt vmcnt(0)" ::: "memory");
    __builtin_amdgcn_s_barrier();
    __builtin_amdgcn_sched_barrier(0);
    CKQ(4, Ra0,Ra1,Ra2,Ra3);
    CKQ(5, Rb0,Rb1,Rb2,Rb3);
#undef STAGE_A
#undef LDCH
#undef CKQ
#undef BODY2

    // epilogue: quad-transpose per nf, + xg(prefetched), cell update
    v4f accA[2] = {acc0, acc1};
    const bool gl0 = lane & 1, gl1 = lane & 2;
    #pragma unroll
    for (int ni = 0; ni < 2; ++ni) {
        float V0 = accA[ni][0], V1 = accA[ni][1];
        float V2 = accA[ni][2], V3 = accA[ni][3];
        float x0 = __shfl_xor(V0, 1), x1 = __shfl_xor(V1, 1);
        float x2 = __shfl_xor(V2, 1), x3 = __shfl_xor(V3, 1);
        float a0 = gl0 ? x1 : V0;
        float a1 = gl0 ? V1 : x0;
        float a2 = gl0 ? x3 : V2;
        float a3 = gl0 ? V3 : x2;
        float s0 = __shfl_xor(a0, 2), s1 = __shfl_xor(a1, 2);
        float s2 = __shfl_xor(a2, 2), s3 = __shfl_xor(a3, 2);
        float Ti = gl1 ? s2 : a0;
        float Tf = gl1 ? s3 : a1;
        float Tc = gl1 ? a2 : s0;
        float To = gl1 ? a3 : s1;

        float pi = Ti + h2f((u16)(xb_pre[ni].x & 0xffff));
        float pf = Tf + h2f((u16)(xb_pre[ni].x >> 16));
        float pc = Tc + h2f((u16)(xb_pre[ni].y & 0xffff));
        float po = To + h2f((u16)(xb_pre[ni].y >> 16));
        float c = hsig(pf) * c_pre[ni] + hsig(pi) * tanhf(pc);
        float h = hsig(po) * tanhf(c);
        cbuf[cidx[ni]] = c;
        u16 hv = f2h(h);
        int fch = f4[ni] >> 2;
        hs16[xrow * 256 + fch] = hv;
        ph_out[(((long)eimg * 18 + (epix >> 4) + 1) * 18 + (epix & 15) + 1) * 256 + fch] = hv;
    }
}

// ---------------------------------------------------------------------------
// t=0 cell: h0=0 -> gates = xg only (no conv). Writes cbuf/hs16/ph_out.
// ---------------------------------------------------------------------------
__global__ __launch_bounds__(256) void gates0_k(
    const u16* __restrict__ xg, float* __restrict__ cbuf,
    u16* __restrict__ hs16, u16* __restrict__ ph_out)
{
    int idx = blockIdx.x * 256 + threadIdx.x;     // 0..262143
    int fch = idx & 255, row = idx >> 8;
    int img = row >> 8, pix = row & 255;
    long xrow = (long)(img * TSTEPS) * HW + pix;
    uint2 xb = *(const uint2*)&xg[xrow * COUT + fch * 4];
    float pi = h2f((u16)(xb.x & 0xffff));
    float pc = h2f((u16)(xb.y & 0xffff));
    float po = h2f((u16)(xb.y >> 16));
    float c = hsig(pi) * tanhf(pc);
    float h = hsig(po) * tanhf(c);
    cbuf[(long)row * 256 + fch] = c;
    u16 hv = f2h(h);
    hs16[xrow * 256 + fch] = hv;
    int yy = pix >> 4, xx = pix & 15;
    ph_out[(((long)img * 18 + yy + 1) * 18 + xx + 1) * 256 + fch] = hv;
}

// ---------------------------------------------------------------------------
// merged weight prep: by<4 -> row-major wT (conv_big); by>=4 -> frag wTf (rec)
// ---------------------------------------------------------------------------
__global__ __launch_bounds__(256) void wprep_all_k(
    const float* __restrict__ wx, const float* __restrict__ wh,
    u16* __restrict__ wT, u16* __restrict__ wTf)
{
    int kq = blockIdx.x;                          // 0..71
    int by = blockIdx.y;                          // 0..19
    if (by < 4) {
        int k0 = kq * 32;
        int np = by * 256 + threadIdx.x;          // n' row
        int n  = (np & 3) * 256 + (np >> 2);
        u32 pk[16];
        #pragma unroll
        for (int kk = 0; kk < 32; kk += 2) {
            float a = wx[(long)(k0 + kk) * COUT + n];
            float b = wx[(long)(k0 + kk + 1) * COUT + n];
            pk[kk >> 1] = (u32)f2h(a) | ((u32)f2h(b) << 16);
        }
        uint4* dst = (uint4*)&wT[(long)np * KTOT + k0];
        dst[0] = make_uint4(pk[0], pk[1], pk[2], pk[3]);
        dst[1] = make_uint4(pk[4], pk[5], pk[6], pk[7]);
        dst[2] = make_uint4(pk[8], pk[9], pk[10], pk[11]);
        dst[3] = make_uint4(pk[12], pk[13], pk[14], pk[15]);
    } else {
        int nf = (by - 4) * 4 + (threadIdx.x >> 6);
        int l  = threadIdx.x & 63;
        int np = nf * 16 + (l & 15);
        int n  = (np & 3) * 256 + (np >> 2);
        int k0 = kq * 32 + (l >> 4) * 8;
        u32 pk[4];
        #pragma unroll
        for (int e = 0; e < 8; e += 2) {
            float a = wh[(long)(k0 + e) * COUT + n];
            float b = wh[(long)(k0 + e + 1) * COUT + n];
            pk[e >> 1] = (u32)f2h(a) | ((u32)f2h(b) << 16);
        }
        *(uint4*)&wTf[((long)(nf * 72) + kq) * 512 + l * 8] =
            make_uint4(pk[0], pk[1], pk[2], pk[3]);
    }
}

// ---------------------------------------------------------------------------
// convert input x (32,16,16,256) fp32 -> pad_x interior fp16
// ---------------------------------------------------------------------------
__global__ __launch_bounds__(256) void convert_x_k(const float* __restrict__ x,
                                                   u16* __restrict__ padx)
{
    int q = blockIdx.x * 256 + threadIdx.x;
    int e0 = q * 4;
    int f = e0 & 255, pix = (e0 >> 8) & 255, img = e0 >> 16;
    float4 v = ((const float4*)x)[q];
    int yy = pix >> 4, xx = pix & 15;
    long o = (((long)img * 18 + yy + 1) * 18 + xx + 1) * 256 + f;
    u32 lo = (u32)f2h(v.x) | ((u32)f2h(v.y) << 16);
    u32 hi = (u32)f2h(v.z) | ((u32)f2h(v.w) << 16);
    *(uint2*)&padx[o] = make_uint2(lo, hi);
}

// ---------------------------------------------------------------------------
// BatchNorm (fp16 h input): deterministic two-stage stats + apply
// ---------------------------------------------------------------------------
__global__ __launch_bounds__(256) void bn_stats1_k(
    const u16* __restrict__ x, float* __restrict__ partial)
{
    const int tid = threadIdx.x;
    const int blk = blockIdx.x;                // 128 blocks
    float s = 0.f, s2 = 0.f;
    const long base = (long)blk * 64 * 256;
    #pragma unroll 8
    for (int gi = 0; gi < 64; ++gi) {
        float v = h2f(x[base + gi * 256 + tid]);
        s += v; s2 += v * v;
    }
    partial[blk * 512 + tid]       = s;
    partial[blk * 512 + 256 + tid] = s2;
}

__global__ __launch_bounds__(256) void bn_stats2_k(
    const float* __restrict__ partial, const float* __restrict__ gamma,
    const float* __restrict__ beta, float* __restrict__ stats)
{
    const int f = threadIdx.x;
    float s = 0.f, s2 = 0.f;
    #pragma unroll 8
    for (int b = 0; b < 128; ++b) {
        s  += partial[b * 512 + f];
        s2 += partial[b * 512 + 256 + f];
    }
    const float inv_n = 1.f / 8192.f;
    float mu  = s * inv_n;
    float var = s2 * inv_n - mu * mu;
    float sc  = gamma[f] * rsqrtf(var + BN_EPS);
    stats[f]       = sc;
    stats[256 + f] = beta[f] - mu * sc;
}

__global__ __launch_bounds__(256) void bn_apply_k(
    const u16* __restrict__ x, const float* __restrict__ stats,
    u16* __restrict__ padx, float* __restrict__ out)
{
    const int q = blockIdx.x * 256 + threadIdx.x;   // 4-channel group
    const int e0 = q * 4;
    const int f = e0 & 255, pix = (e0 >> 8) & 255, img = e0 >> 16;
    ushort4 hv = ((const ushort4*)x)[q];
    float4 v = make_float4(h2f(hv.x), h2f(hv.y), h2f(hv.z), h2f(hv.w));
    float4 sc = *(const float4*)(stats + f);
    float4 sh = *(const float4*)(stats + 256 + f);
    v.x = v.x * sc.x + sh.x;
    v.y = v.y * sc.y + sh.y;
    v.z = v.z * sc.z + sh.z;
    v.w = v.w * sc.w + sh.w;
    if (out) ((float4*)out)[q] = v;
    if (padx) {
        int yy = pix >> 4, xx = pix & 15;
        long o = (((long)img * 18 + yy + 1) * 18 + xx + 1) * 256 + f;
        u32 lo = (u32)f2h(v.x) | ((u32)f2h(v.y) << 16);
        u32 hi = (u32)f2h(v.z) | ((u32)f2h(v.w) << 16);
        *(uint2*)&padx[o] = make_uint2(lo, hi);
    }
}

// ---------------------------------------------------------------------------
extern "C" void kernel_launch(void* const* d_in, const int* in_sizes, int n_in,
                              void* d_out, int out_size, void* d_ws, size_t ws_size,
                              hipStream_t stream)
{
    const float* x0    = (const float*)d_in[0];
    const float* Wx[3] = {(const float*)d_in[1], (const float*)d_in[6],  (const float*)d_in[11]};
    const float* Wh[3] = {(const float*)d_in[2], (const float*)d_in[7],  (const float*)d_in[12]};
    const float* bb[3] = {(const float*)d_in[3], (const float*)d_in[8],  (const float*)d_in[13]};
    const float* gg[3] = {(const float*)d_in[4], (const float*)d_in[9],  (const float*)d_in[14]};
    const float* be[3] = {(const float*)d_in[5], (const float*)d_in[10], (const float*)d_in[15]};

    float* ws    = (float*)d_ws;
    u16*  xg     = (u16*)ws;              // 8,388,608 u16 (8192 x 1024 fp16, n')
    float* cbuf  = ws   + 4194304;        //   262,144 f32
    u16*  hs16   = (u16*)(cbuf + 262144); // 2,097,152 u16 (8192 x 256 fp16)
    float* part  = (float*)(hs16 + 2097152); //  65,536 (128 x 512)
    float* stats = part + 65536;          //       512
    u16*  pad_x  = (u16*)(stats + 512);   // 32*18*18*256 fp16
    u16*  pad_h  = pad_x + 2654208;       // 2 x 331,776 (ping-pong)
    u16*  wTx    = pad_h + 663552;        // 1024*2304 (row-major, conv_big)
    u16*  wTf    = wTx   + 2359296;       // 64*72*512 (frag-packed, rec)
    const long PHN = 331776;

    hipMemsetAsync(pad_x, 0, 2654208 * sizeof(u16), stream);   // halos
    hipMemsetAsync(pad_h, 0, 2 * PHN * sizeof(u16), stream);   // halos (once)
    hipLaunchKernelGGL(convert_x_k, dim3(2048), dim3(256), 0, stream, x0, pad_x);

    for (int l = 0; l < 3; ++l) {
        hipLaunchKernelGGL(wprep_all_k, dim3(72, 20), dim3(256), 0, stream,
            Wx[l], Wh[l], wTx, wTf);

        hipLaunchKernelGGL(conv_big_k, dim3(512), dim3(256), 0, stream,
            pad_x, wTx, bb[l], xg);

        // t = 0: gates-only (h0 = 0); writes cbuf/hs16/ph buffer 1
        hipLaunchKernelGGL(gates0_k, dim3(1024), dim3(256), 0, stream,
            xg, cbuf, hs16, pad_h + PHN);

        for (int t = 1; t < TSTEPS; ++t) {
            hipLaunchKernelGGL(rec_fused_k, dim3(512), dim3(256), 0, stream,
                pad_h + (t & 1) * PHN, wTf, xg, cbuf, hs16,
                pad_h + ((t & 1) ^ 1) * PHN, t);
        }

        hipLaunchKernelGGL(bn_stats1_k, dim3(128), dim3(256), 0, stream, hs16, part);
        hipLaunchKernelGGL(bn_stats2_k, dim3(1), dim3(256), 0, stream, part, gg[l], be[l], stats);
        hipLaunchKernelGGL(bn_apply_k, dim3(2048), dim3(256), 0, stream, hs16, stats,
            (l < 2) ? pad_x : (u16*)nullptr, (l == 2) ? (float*)d_out : (float*)nullptr);
    }
}

// Round 17
// 519.001 us; speedup vs baseline: 1.0194x; 1.0194x over previous
//
#include <hip/hip_runtime.h>

// B=4, T=8, H=W=16, C=F=256, gates 4F=1024. K = 9*256 = 2304.
// Round 17: rec reverted to r15 v10 (64x64, 256 blocks, 8 waves — best
// measured). conv_big v2: operand split like rec — B (Wx) frag-packed,
// read from L2 into regs (3-set rotation); A-only LDS (6 x 16KB ring),
// 512 threads (8 waves 2x4, wave 64m x 32n), 1 blk/CU, vmcnt(12),
// by-per-XCD mapping. wprep emits BOTH frag-packed tables.
#define HW      256
#define COUT    1024
#define TSTEPS  8
#define BN_EPS  1e-3f
#define KTOT    2304

typedef unsigned short u16;
typedef unsigned int   u32;
typedef __attribute__((ext_vector_type(8))) _Float16 v8h;  // 8 x fp16
typedef __attribute__((ext_vector_type(4))) float v4f;

__device__ __forceinline__ u16 f2h(float x) {
    _Float16 h = (_Float16)x; return *(u16*)&h;
}
__device__ __forceinline__ float h2f(u16 u) {
    _Float16 h = *(_Float16*)&u; return (float)h;
}
__device__ __forceinline__ float hsig(float x) {
    return fminf(fmaxf(0.2f * x + 0.5f, 0.f), 1.f);
}

typedef __attribute__((address_space(1))) const unsigned int gas_u32;
typedef __attribute__((address_space(3))) unsigned int las_u32;
__device__ __forceinline__ void gl16(const void* g, void* l) {
    __builtin_amdgcn_global_load_lds((gas_u32*)g, (las_u32*)l, 16, 0, 0);
}

// ---------------------------------------------------------------------------
// Big input conv v2: M=8192, N'=1024, BM=128, BN=128, 512 threads
// (8 waves 2x4; wave 64m x 32n). B frag-packed from L2 into regs
// (3-set rotation); A gl16->LDS 6-buffer ring (16KB each); K128 bodies,
// 18 barriers, uniform vmcnt(12). Grid 512: by = bid&7 (one by per XCD).
// ---------------------------------------------------------------------------
__global__ __launch_bounds__(512, 1) void conv_big_k(
    const u16* __restrict__ apad,     // (32,18,18,256) fp16 zero-padded
    const u16* __restrict__ wTxf,     // frag-packed Wx: (64 nf, 72 kq, 512)
    const float* __restrict__ bias,   // (1024) original n order
    u16* __restrict__ out)            // (8192, 1024) fp16, n' order
{
    __shared__ u16 lds[6 * 8192];     // 6 bufs x 16KB (A only), 96KB

    const int bid = blockIdx.x;
    const int by = bid & 7, bx = bid >> 3;      // by per XCD; bx 0..63
    const int m0 = bx * 128, n0 = by * 128;
    const int tid = threadIdx.x, lane = tid & 63, w = tid >> 6;
    const int wr = w >> 2, wc = w & 3;          // 2 x 4 wave grid
    const int fr = lane & 15, kc = lane >> 4;

    // A staging: wave w stages rows w*16..w*16+15 (2 gl16 per thread)
    const char *a_src0, *a_src1;
    {
        int gg = (lane & 7) ^ (lane >> 3);      // inverse swizzle granule
        int rt = w * 16 + (lane >> 3);
        int m = m0 + rt;
        int img = m >> 8, pix = m & 255, yy = pix >> 4, xx = pix & 15;
        a_src0 = (const char*)apad + ((((long)img * 18 + yy) * 18 + xx) * 256 + gg * 8) * 2;
        m += 8; img = m >> 8; pix = m & 255; yy = pix >> 4; xx = pix & 15;
        a_src1 = (const char*)apad + ((((long)img * 18 + yy) * 18 + xx) * 256 + gg * 8) * 2;
    }
    // B fragment bases: wave covers nf = by*8 + wc*2 + {0,1}
    const char* bb0 = (const char*)wTxf + ((long)(by * 8 + wc * 2) * 72) * 1024 + lane * 16;
    const char* bb1 = bb0 + 72 * 1024;

    // A frag read offsets (swizzled slot), rows wr*64 + mi*16 + fr
    int aro[4][2];
    #pragma unroll
    for (int mi = 0; mi < 4; ++mi)
        #pragma unroll
        for (int ks = 0; ks < 2; ++ks)
            aro[mi][ks] = (wr * 64 + mi * 16 + fr) * 128 + ((((ks << 2) | kc) ^ (fr & 7)) << 4);

    v4f acc[4][2];
    #pragma unroll
    for (int mi = 0; mi < 4; ++mi) {
        acc[mi][0] = (v4f)0.f;
        acc[mi][1] = (v4f)0.f;
    }

// stage K64 chunk C into 16KB buffer BUF (2 gl16 per thread)
#define STAGE_C(C, BUF) { int c_ = (C); int dxy = c_ >> 2, c64 = c_ & 3;      \
    int dy = (dxy * 11) >> 5; int dx = dxy - dy * 3;                          \
    int aoff = ((dy * 18 + dx) * 256 + c64 * 64) * 2;                         \
    char* dst = (char*)lds + (BUF) * 16384 + w * 2048;                        \
    gl16(a_src0 + aoff, dst); gl16(a_src1 + aoff, dst + 1024); }

// load K64 chunk C's B frags: R0/R1 = kq even (nf0,nf1), R2/R3 = kq odd
#define LDCH(C, R0, R1, R2, R3) { int kq_ = 2 * (C);                          \
    R0 = *(const v8h*)(bb0 + (long)kq_ * 1024);                               \
    R1 = *(const v8h*)(bb1 + (long)kq_ * 1024);                               \
    R2 = *(const v8h*)(bb0 + (long)(kq_ + 1) * 1024);                         \
    R3 = *(const v8h*)(bb1 + (long)(kq_ + 1) * 1024); }

// compute one K64 chunk from buffer BUF (8 A reads, 16 MFMA)
#define CCH(BUF, R0, R1, R2, R3) {                                            \
    const char* base_ = (const char*)lds + (BUF) * 16384;                     \
    v8h a00_ = *(const v8h*)(base_ + aro[0][0]);                              \
    v8h a10_ = *(const v8h*)(base_ + aro[1][0]);                              \
    v8h a20_ = *(const v8h*)(base_ + aro[2][0]);                              \
    v8h a30_ = *(const v8h*)(base_ + aro[3][0]);                              \
    __builtin_amdgcn_s_setprio(1);                                            \
    acc[0][0] = __builtin_amdgcn_mfma_f32_16x16x32_f16(a00_, R0, acc[0][0], 0, 0, 0); \
    acc[0][1] = __builtin_amdgcn_mfma_f32_16x16x32_f16(a00_, R1, acc[0][1], 0, 0, 0); \
    acc[1][0] = __builtin_amdgcn_mfma_f32_16x16x32_f16(a10_, R0, acc[1][0], 0, 0, 0); \
    acc[1][1] = __builtin_amdgcn_mfma_f32_16x16x32_f16(a10_, R1, acc[1][1], 0, 0, 0); \
    acc[2][0] = __builtin_amdgcn_mfma_f32_16x16x32_f16(a20_, R0, acc[2][0], 0, 0, 0); \
    acc[2][1] = __builtin_amdgcn_mfma_f32_16x16x32_f16(a20_, R1, acc[2][1], 0, 0, 0); \
    acc[3][0] = __builtin_amdgcn_mfma_f32_16x16x32_f16(a30_, R0, acc[3][0], 0, 0, 0); \
    acc[3][1] = __builtin_amdgcn_mfma_f32_16x16x32_f16(a30_, R1, acc[3][1], 0, 0, 0); \
    __builtin_amdgcn_s_setprio(0);                                            \
    v8h a01_ = *(const v8h*)(base_ + aro[0][1]);                              \
    v8h a11_ = *(const v8h*)(base_ + aro[1][1]);                              \
    v8h a21_ = *(const v8h*)(base_ + aro[2][1]);                              \
    v8h a31_ = *(const v8h*)(base_ + aro[3][1]);                              \
    __builtin_amdgcn_s_setprio(1);                                            \
    acc[0][0] = __builtin_amdgcn_mfma_f32_16x16x32_f16(a01_, R2, acc[0][0], 0, 0, 0); \
    acc[0][1] = __builtin_amdgcn_mfma_f32_16x16x32_f16(a01_, R3, acc[0][1], 0, 0, 0); \
    acc[1][0] = __builtin_amdgcn_mfma_f32_16x16x32_f16(a11_, R2, acc[1][0], 0, 0, 0); \
    acc[1][1] = __builtin_amdgcn_mfma_f32_16x16x32_f16(a11_, R3, acc[1][1], 0, 0, 0); \
    acc[2][0] = __builtin_amdgcn_mfma_f32_16x16x32_f16(a21_, R2, acc[2][0], 0, 0, 0); \
    acc[2][1] = __builtin_amdgcn_mfma_f32_16x16x32_f16(a21_, R3, acc[2][1], 0, 0, 0); \
    acc[3][0] = __builtin_amdgcn_mfma_f32_16x16x32_f16(a31_, R2, acc[3][0], 0, 0, 0); \
    acc[3][1] = __builtin_amdgcn_mfma_f32_16x16x32_f16(a31_, R3, acc[3][1], 0, 0, 0); \
    __builtin_amdgcn_s_setprio(0); }

// body J: compute chunks 2J,2J+1 from bufs BC,BC+1; load+stage chunks
// 2J+4,2J+5 into L-sets and bufs BS,BS+1. 12 VMEM ops per body.
#define BODY_C(J, BC, BS, A0,A1,A2,A3, B0,B1,B2,B3, LA0,LA1,LA2,LA3, LB0,LB1,LB2,LB3) { \
    int c0_ = 2 * (J);                                                        \
    asm volatile("s_waitcnt vmcnt(12)" ::: "memory");                         \
    __builtin_amdgcn_s_barrier();                                             \
    __builtin_amdgcn_sched_barrier(0);                                        \
    LDCH(c0_ + 4, LA0, LA1, LA2, LA3);                                        \
    LDCH(c0_ + 5, LB0, LB1, LB2, LB3);                                        \
    STAGE_C(c0_ + 4, BS); STAGE_C(c0_ + 5, (BS) + 1);                         \
    CCH(BC,       A0, A1, A2, A3);                                            \
    CCH((BC) + 1, B0, B1, B2, B3); }

    v8h Pa0,Pa1,Pa2,Pa3, Pb0,Pb1,Pb2,Pb3;
    v8h Qa0,Qa1,Qa2,Qa3, Qb0,Qb1,Qb2,Qb3;
    v8h Ra0,Ra1,Ra2,Ra3, Rb0,Rb1,Rb2,Rb3;
    // prologue: body0 (chunks 0,1 -> bufs 0,1), body1 (chunks 2,3 -> bufs 2,3)
    LDCH(0, Pa0,Pa1,Pa2,Pa3); LDCH(1, Pb0,Pb1,Pb2,Pb3);
    STAGE_C(0, 0); STAGE_C(1, 1);
    LDCH(2, Qa0,Qa1,Qa2,Qa3); LDCH(3, Qb0,Qb1,Qb2,Qb3);
    STAGE_C(2, 2); STAGE_C(3, 3);

    for (int j = 0; j < 5; ++j) {        // bodies 0..14
        BODY_C(3 * j,     0, 4, Pa0,Pa1,Pa2,Pa3, Pb0,Pb1,Pb2,Pb3,
                                Ra0,Ra1,Ra2,Ra3, Rb0,Rb1,Rb2,Rb3);
        BODY_C(3 * j + 1, 2, 0, Qa0,Qa1,Qa2,Qa3, Qb0,Qb1,Qb2,Qb3,
                                Pa0,Pa1,Pa2,Pa3, Pb0,Pb1,Pb2,Pb3);
        BODY_C(3 * j + 2, 4, 2, Ra0,Ra1,Ra2,Ra3, Rb0,Rb1,Rb2,Rb3,
                                Qa0,Qa1,Qa2,Qa3, Qb0,Qb1,Qb2,Qb3);
    }
    // body 15 (chunks 30,31 from bufs 0,1; stages 34,35 into bufs 4,5)
    BODY_C(15, 0, 4, Pa0,Pa1,Pa2,Pa3, Pb0,Pb1,Pb2,Pb3,
                     Ra0,Ra1,Ra2,Ra3, Rb0,Rb1,Rb2,Rb3);
    // body 16 (chunks 32,33 from bufs 2,3; no issue)
    asm volatile("s_waitcnt vmcnt(12)" ::: "memory");
    __builtin_amdgcn_s_barrier();
    __builtin_amdgcn_sched_barrier(0);
    CCH(2, Qa0,Qa1,Qa2,Qa3);
    CCH(3, Qb0,Qb1,Qb2,Qb3);
    // body 17 (chunks 34,35 from bufs 4,5; no issue)
    asm volatile("s_waitcnt vmcnt(0)" ::: "memory");
    __builtin_amdgcn_s_barrier();
    __builtin_amdgcn_sched_barrier(0);
    CCH(4, Ra0,Ra1,Ra2,Ra3);
    CCH(5, Rb0,Rb1,Rb2,Rb3);
#undef STAGE_C
#undef LDCH
#undef CCH
#undef BODY_C

    // epilogue: +bias (remapped n' -> n), store fp16 n'-order
    #pragma unroll
    for (int mi = 0; mi < 4; ++mi) {
        #pragma unroll
        for (int ni = 0; ni < 2; ++ni) {
            int mrow = m0 + wr * 64 + mi * 16 + ((lane >> 4) << 2);
            int ncol = n0 + wc * 32 + ni * 16 + fr;
            float b0 = bias[(ncol & 3) * 256 + (ncol >> 2)];
            #pragma unroll
            for (int r = 0; r < 4; ++r)
                out[(long)(mrow + r) * COUT + ncol] = f2h(acc[mi][ni][r] + b0);
        }
    }
}

// ---------------------------------------------------------------------------
// Recurrent conv + fused LSTM cell, v10 (r15, best measured): 64x64 tile,
// 256 blocks, 8 waves, BK=128 bodies, 6-buffer LDS ring, uniform vmcnt(6),
// xg + cbuf prefetch issued first, hs fp16.
// ---------------------------------------------------------------------------
__global__ __launch_bounds__(512) void rec_fused_k(
    const u16* __restrict__ ph_in,    // (4,18,18,256) fp16  h_{t-1}
    const u16* __restrict__ wTf,      // frag-packed Wh: (64 nf, 72 k32, 512)
    const u16* __restrict__ xg,       // (8192, 1024) fp16, n' order (incl bias)
    float* __restrict__ cbuf,         // (4,256,256)
    u16* __restrict__ hs16,           // (8192,256) fp16
    u16* __restrict__ ph_out,         // (4,18,18,256) fp16  h_t
    int t)
{
    __shared__ u16 lds[6 * 4096];     // 6 bufs x 8KB (A only), 48KB

    const int bid = blockIdx.x;       // 256: by-pairs per XCD (bijective)
    const int by = (bid & 7) * 2 + ((bid >> 3) & 1);   // 0..15
    const int bx = bid >> 4;                           // 0..15
    const int m0 = bx * 64, n0 = by * 64;
    const int tid = threadIdx.x, lane = tid & 63, w = tid >> 6;
    const int wr = w >> 2, wc = w & 3;
    const int fr = lane & 15, kc = lane >> 4;

    // epilogue coordinates (fixed) — xg + cbuf prefetch issued FIRST
    const int f4  = n0 + wc * 16 + (lane & 12);
    const int fch = f4 >> 2;
    int erow[2]; long xrow[2], cidx[2];
    uint2 xb_pre[2];
    float c_pre[2];
    #pragma unroll
    for (int mi = 0; mi < 2; ++mi) {
        erow[mi] = m0 + wr * 32 + mi * 16 + ((lane >> 4) << 2) + (lane & 3);
        int img = erow[mi] >> 8, pix = erow[mi] & 255;
        xrow[mi] = ((long)(img * TSTEPS + t) * HW + pix);
        cidx[mi] = (long)erow[mi] * 256 + fch;
        xb_pre[mi] = *(const uint2*)&xg[xrow[mi] * COUT + f4];
        c_pre[mi]  = cbuf[cidx[mi]];
    }

    // A staging: thread stages row rt = tid>>3 (0..63), slot lane&7
    const char* a_src;
    {
        int rt = tid >> 3;
        int gg = (tid & 7) ^ (rt & 7);     // inverse swizzle on SOURCE granule
        int m = m0 + rt;
        int img = m >> 8, pix = m & 255, yy = pix >> 4, xx = pix & 15;
        a_src = (const char*)ph_in + ((((long)img * 18 + yy) * 18 + xx) * 256 + gg * 8) * 2;
    }
    // B fragment base: wave-col owns nf = by*4 + wc
    const char* b_base = (const char*)wTf + ((long)(by * 4 + wc) * 72) * 1024 + lane * 16;

    // A frag read offsets (swizzled slot), rows wr*32 + mi*16 + fr
    int aro[2][2];
    #pragma unroll
    for (int mi = 0; mi < 2; ++mi)
        #pragma unroll
        for (int ks = 0; ks < 2; ++ks)
            aro[mi][ks] = (wr * 32 + mi * 16 + fr) * 128 + ((((ks << 2) | kc) ^ (fr & 7)) << 4);

    v4f acc0 = (v4f)0.f, acc1 = (v4f)0.f;

#define STAGE_A(J, BUF) { int j_ = (J); int dxy = j_ >> 2, c64 = j_ & 3;      \
    int dy = (dxy * 11) >> 5; int dx = dxy - dy * 3;                          \
    int aoff = ((dy * 18 + dx) * 256 + c64 * 64) * 2;                         \
    gl16(a_src + aoff, (char*)lds + (BUF) * 8192 + w * 1024); }

#define LDB(J, R0, R1) { R0 = *(const v8h*)(b_base + (2 * (J)) * 1024);       \
                         R1 = *(const v8h*)(b_base + (2 * (J) + 1) * 1024); }

#define CKQ(BUF, C0, C1) {                                                    \
    const char* base_ = (const char*)lds + (BUF) * 8192;                      \
    v8h af00_ = *(const v8h*)(base_ + aro[0][0]);                             \
    v8h af10_ = *(const v8h*)(base_ + aro[1][0]);                             \
    v8h af01_ = *(const v8h*)(base_ + aro[0][1]);                             \
    v8h af11_ = *(const v8h*)(base_ + aro[1][1]);                             \
    __builtin_amdgcn_s_setprio(1);                                            \
    acc0 = __builtin_amdgcn_mfma_f32_16x16x32_f16(af00_, C0, acc0, 0, 0, 0);  \
    acc1 = __builtin_amdgcn_mfma_f32_16x16x32_f16(af10_, C0, acc1, 0, 0, 0);  \
    acc0 = __builtin_amdgcn_mfma_f32_16x16x32_f16(af01_, C1, acc0, 0, 0, 0);  \
    acc1 = __builtin_amdgcn_mfma_f32_16x16x32_f16(af11_, C1, acc1, 0, 0, 0);  \
    __builtin_amdgcn_s_setprio(0); }

#define BODY2(J2, BC, BS, Ca0, Ca1, Cb0, Cb1, La0, La1, Lb0, Lb1) {           \
    int q0_ = 2 * (J2);                                                       \
    asm volatile("s_waitcnt vmcnt(6)" ::: "memory");                          \
    __builtin_amdgcn_s_barrier();                                             \
    __builtin_amdgcn_sched_barrier(0);                                        \
    LDB(q0_ + 4, La0, La1); LDB(q0_ + 5, Lb0, Lb1);                           \
    STAGE_A(q0_ + 4, BS); STAGE_A(q0_ + 5, (BS) + 1);                         \
    CKQ(BC,       Ca0, Ca1);                                                  \
    CKQ((BC) + 1, Cb0, Cb1); }

    v8h S00, S01, S02, S03, S10, S11, S12, S13, S20, S21, S22, S23;
    // prologue: body0 data then body1 data (bufs 0..3)
    LDB(0, S00, S01); LDB(1, S02, S03); STAGE_A(0, 0); STAGE_A(1, 1);
    LDB(2, S10, S11); LDB(3, S12, S13); STAGE_A(2, 2); STAGE_A(3, 3);

    for (int j = 0; j < 5; ++j) {        // bodies 0..14 (kq advances 6 per j)
        BODY2(3 * j,     0, 4, S00, S01, S02, S03, S20, S21, S22, S23);
        BODY2(3 * j + 1, 2, 0, S10, S11, S12, S13, S00, S01, S02, S03);
        BODY2(3 * j + 2, 4, 2, S20, S21, S22, S23, S10, S11, S12, S13);
    }
    // body 15 (kq 30,31 from bufs 0,1; stages kq 34,35 into bufs 4,5)
    BODY2(15, 0, 4, S00, S01, S02, S03, S20, S21, S22, S23);
    // body 16 (kq 32,33 from bufs 2,3; no issue)
    asm volatile("s_waitcnt vmcnt(6)" ::: "memory");
    __builtin_amdgcn_s_barrier();
    __builtin_amdgcn_sched_barrier(0);
    CKQ(2, S10, S11);
    CKQ(3, S12, S13);
    // body 17 (kq 34,35 from bufs 4,5; no issue)
    asm volatile("s_waitcnt vmcnt(0)" ::: "memory");
    __builtin_amdgcn_s_barrier();
    __builtin_amdgcn_sched_barrier(0);
    CKQ(4, S20, S21);
    CKQ(5, S22, S23);
#undef STAGE_A
#undef LDB
#undef CKQ
#undef BODY2

    // epilogue: quad-transpose, + xg(prefetched), cell update (c prefetched)
    v4f accA[2] = {acc0, acc1};
    const bool gl0 = lane & 1, gl1 = lane & 2;
    #pragma unroll
    for (int mi = 0; mi < 2; ++mi) {
        float V0 = accA[mi][0], V1 = accA[mi][1];
        float V2 = accA[mi][2], V3 = accA[mi][3];
        float x0 = __shfl_xor(V0, 1), x1 = __shfl_xor(V1, 1);
        float x2 = __shfl_xor(V2, 1), x3 = __shfl_xor(V3, 1);
        float a0 = gl0 ? x1 : V0;
        float a1 = gl0 ? V1 : x0;
        float a2 = gl0 ? x3 : V2;
        float a3 = gl0 ? V3 : x2;
        float s0 = __shfl_xor(a0, 2), s1 = __shfl_xor(a1, 2);
        float s2 = __shfl_xor(a2, 2), s3 = __shfl_xor(a3, 2);
        float Ti = gl1 ? s2 : a0;
        float Tf = gl1 ? s3 : a1;
        float Tc = gl1 ? a2 : s0;
        float To = gl1 ? a3 : s1;

        float pi = Ti + h2f((u16)(xb_pre[mi].x & 0xffff));
        float pf = Tf + h2f((u16)(xb_pre[mi].x >> 16));
        float pc = Tc + h2f((u16)(xb_pre[mi].y & 0xffff));
        float po = To + h2f((u16)(xb_pre[mi].y >> 16));
        float c = hsig(pf) * c_pre[mi] + hsig(pi) * tanhf(pc);
        float h = hsig(po) * tanhf(c);
        cbuf[cidx[mi]] = c;
        u16 hv = f2h(h);
        hs16[xrow[mi] * 256 + fch] = hv;
        int pix = erow[mi] & 255, img = erow[mi] >> 8;
        ph_out[(((long)img * 18 + (pix >> 4) + 1) * 18 + (pix & 15) + 1) * 256 + fch] = hv;
    }
}

// ---------------------------------------------------------------------------
// t=0 cell: h0=0 -> gates = xg only (no conv). Writes cbuf/hs16/ph_out.
// ---------------------------------------------------------------------------
__global__ __launch_bounds__(256) void gates0_k(
    const u16* __restrict__ xg, float* __restrict__ cbuf,
    u16* __restrict__ hs16, u16* __restrict__ ph_out)
{
    int idx = blockIdx.x * 256 + threadIdx.x;     // 0..262143
    int fch = idx & 255, row = idx >> 8;
    int img = row >> 8, pix = row & 255;
    long xrow = (long)(img * TSTEPS) * HW + pix;
    uint2 xb = *(const uint2*)&xg[xrow * COUT + fch * 4];
    float pi = h2f((u16)(xb.x & 0xffff));
    float pc = h2f((u16)(xb.y & 0xffff));
    float po = h2f((u16)(xb.y >> 16));
    float c = hsig(pi) * tanhf(pc);
    float h = hsig(po) * tanhf(c);
    cbuf[(long)row * 256 + fch] = c;
    u16 hv = f2h(h);
    hs16[xrow * 256 + fch] = hv;
    int yy = pix >> 4, xx = pix & 15;
    ph_out[(((long)img * 18 + yy + 1) * 18 + xx + 1) * 256 + fch] = hv;
}

// ---------------------------------------------------------------------------
// merged weight prep: both tables frag-packed (64 nf, 72 kq, 512).
// by<16 -> wTxf (from Wx); by>=16 -> wTf (from Wh).
// ---------------------------------------------------------------------------
__global__ __launch_bounds__(256) void wprep_all_k(
    const float* __restrict__ wx, const float* __restrict__ wh,
    u16* __restrict__ wTxf, u16* __restrict__ wTf)
{
    int kq = blockIdx.x;                          // 0..71
    int by = blockIdx.y;                          // 0..31
    const float* src = (by < 16) ? wx : wh;
    u16* dst = (by < 16) ? wTxf : wTf;
    int nf = ((by & 15) * 4) + (threadIdx.x >> 6);
    int l  = threadIdx.x & 63;
    int np = nf * 16 + (l & 15);
    int n  = (np & 3) * 256 + (np >> 2);
    int k0 = kq * 32 + (l >> 4) * 8;
    u32 pk[4];
    #pragma unroll
    for (int e = 0; e < 8; e += 2) {
        float a = src[(long)(k0 + e) * COUT + n];
        float b = src[(long)(k0 + e + 1) * COUT + n];
        pk[e >> 1] = (u32)f2h(a) | ((u32)f2h(b) << 16);
    }
    *(uint4*)&dst[((long)(nf * 72) + kq) * 512 + l * 8] =
        make_uint4(pk[0], pk[1], pk[2], pk[3]);
}

// ---------------------------------------------------------------------------
// convert input x (32,16,16,256) fp32 -> pad_x interior fp16
// ---------------------------------------------------------------------------
__global__ __launch_bounds__(256) void convert_x_k(const float* __restrict__ x,
                                                   u16* __restrict__ padx)
{
    int q = blockIdx.x * 256 + threadIdx.x;
    int e0 = q * 4;
    int f = e0 & 255, pix = (e0 >> 8) & 255, img = e0 >> 16;
    float4 v = ((const float4*)x)[q];
    int yy = pix >> 4, xx = pix & 15;
    long o = (((long)img * 18 + yy + 1) * 18 + xx + 1) * 256 + f;
    u32 lo = (u32)f2h(v.x) | ((u32)f2h(v.y) << 16);
    u32 hi = (u32)f2h(v.z) | ((u32)f2h(v.w) << 16);
    *(uint2*)&padx[o] = make_uint2(lo, hi);
}

// ---------------------------------------------------------------------------
// BatchNorm (fp16 h input): deterministic two-stage stats + apply
// ---------------------------------------------------------------------------
__global__ __launch_bounds__(256) void bn_stats1_k(
    const u16* __restrict__ x, float* __restrict__ partial)
{
    const int tid = threadIdx.x;
    const int blk = blockIdx.x;                // 128 blocks
    float s = 0.f, s2 = 0.f;
    const long base = (long)blk * 64 * 256;
    #pragma unroll 8
    for (int gi = 0; gi < 64; ++gi) {
        float v = h2f(x[base + gi * 256 + tid]);
        s += v; s2 += v * v;
    }
    partial[blk * 512 + tid]       = s;
    partial[blk * 512 + 256 + tid] = s2;
}

__global__ __launch_bounds__(256) void bn_stats2_k(
    const float* __restrict__ partial, const float* __restrict__ gamma,
    const float* __restrict__ beta, float* __restrict__ stats)
{
    const int f = threadIdx.x;
    float s = 0.f, s2 = 0.f;
    #pragma unroll 8
    for (int b = 0; b < 128; ++b) {
        s  += partial[b * 512 + f];
        s2 += partial[b * 512 + 256 + f];
    }
    const float inv_n = 1.f / 8192.f;
    float mu  = s * inv_n;
    float var = s2 * inv_n - mu * mu;
    float sc  = gamma[f] * rsqrtf(var + BN_EPS);
    stats[f]       = sc;
    stats[256 + f] = beta[f] - mu * sc;
}

__global__ __launch_bounds__(256) void bn_apply_k(
    const u16* __restrict__ x, const float* __restrict__ stats,
    u16* __restrict__ padx, float* __restrict__ out)
{
    const int q = blockIdx.x * 256 + threadIdx.x;   // 4-channel group
    const int e0 = q * 4;
    const int f = e0 & 255, pix = (e0 >> 8) & 255, img = e0 >> 16;
    ushort4 hv = ((const ushort4*)x)[q];
    float4 v = make_float4(h2f(hv.x), h2f(hv.y), h2f(hv.z), h2f(hv.w));
    float4 sc = *(const float4*)(stats + f);
    float4 sh = *(const float4*)(stats + 256 + f);
    v.x = v.x * sc.x + sh.x;
    v.y = v.y * sc.y + sh.y;
    v.z = v.z * sc.z + sh.z;
    v.w = v.w * sc.w + sh.w;
    if (out) ((float4*)out)[q] = v;
    if (padx) {
        int yy = pix >> 4, xx = pix & 15;
        long o = (((long)img * 18 + yy + 1) * 18 + xx + 1) * 256 + f;
        u32 lo = (u32)f2h(v.x) | ((u32)f2h(v.y) << 16);
        u32 hi = (u32)f2h(v.z) | ((u32)f2h(v.w) << 16);
        *(uint2*)&padx[o] = make_uint2(lo, hi);
    }
}

// ---------------------------------------------------------------------------
extern "C" void kernel_launch(void* const* d_in, const int* in_sizes, int n_in,
                              void* d_out, int out_size, void* d_ws, size_t ws_size,
                              hipStream_t stream)
{
    const float* x0    = (const float*)d_in[0];
    const float* Wx[3] = {(const float*)d_in[1], (const float*)d_in[6],  (const float*)d_in[11]};
    const float* Wh[3] = {(const float*)d_in[2], (const float*)d_in[7],  (const float*)d_in[12]};
    const float* bb[3] = {(const float*)d_in[3], (const float*)d_in[8],  (const float*)d_in[13]};
    const float* gg[3] = {(const float*)d_in[4], (const float*)d_in[9],  (const float*)d_in[14]};
    const float* be[3] = {(const float*)d_in[5], (const float*)d_in[10], (const float*)d_in[15]};

    float* ws    = (float*)d_ws;
    u16*  xg     = (u16*)ws;              // 8,388,608 u16 (8192 x 1024 fp16, n')
    float* cbuf  = ws   + 4194304;        //   262,144 f32
    u16*  hs16   = (u16*)(cbuf + 262144); // 2,097,152 u16 (8192 x 256 fp16)
    float* part  = (float*)(hs16 + 2097152); //  65,536 (128 x 512)
    float* stats = part + 65536;          //       512
    u16*  pad_x  = (u16*)(stats + 512);   // 32*18*18*256 fp16
    u16*  pad_h  = pad_x + 2654208;       // 2 x 331,776 (ping-pong)
    u16*  wTxf   = pad_h + 663552;        // 64*72*512 (frag-packed, conv)
    u16*  wTf    = wTxf  + 2359296;       // 64*72*512 (frag-packed, rec)
    const long PHN = 331776;

    hipMemsetAsync(pad_x, 0, 2654208 * sizeof(u16), stream);   // halos
    hipMemsetAsync(pad_h, 0, 2 * PHN * sizeof(u16), stream);   // halos (once)
    hipLaunchKernelGGL(convert_x_k, dim3(2048), dim3(256), 0, stream, x0, pad_x);

    for (int l = 0; l < 3; ++l) {
        hipLaunchKernelGGL(wprep_all_k, dim3(72, 32), dim3(256), 0, stream,
            Wx[l], Wh[l], wTxf, wTf);

        hipLaunchKernelGGL(conv_big_k, dim3(512), dim3(512), 0, stream,
            pad_x, wTxf, bb[l], xg);

        // t = 0: gates-only (h0 = 0); writes cbuf/hs16/ph buffer 1
        hipLaunchKernelGGL(gates0_k, dim3(1024), dim3(256), 0, stream,
            xg, cbuf, hs16, pad_h + PHN);

        for (int t = 1; t < TSTEPS; ++t) {
            hipLaunchKernelGGL(rec_fused_k, dim3(256), dim3(512), 0, stream,
                pad_h + (t & 1) * PHN, wTf, xg, cbuf, hs16,
                pad_h + ((t & 1) ^ 1) * PHN, t);
        }

        hipLaunchKernelGGL(bn_stats1_k, dim3(128), dim3(256), 0, stream, hs16, part);
        hipLaunchKernelGGL(bn_stats2_k, dim3(1), dim3(256), 0, stream, part, gg[l], be[l], stats);
        hipLaunchKernelGGL(bn_apply_k, dim3(2048), dim3(256), 0, stream, hs16, stats,
            (l < 2) ? pad_x : (u16*)nullptr, (l == 2) ? (float*)d_out : (float*)nullptr);
    }
}

// Round 18
// 471.420 us; speedup vs baseline: 1.1223x; 1.1009x over previous
//
#include <hip/hip_runtime.h>

// B=4, T=8, H=W=16, C=F=256, gates 4F=1024. K = 9*256 = 2304.
// Round 18: restore best-measured configuration (r11, 470.3us):
// conv_big = r6 single-barrier depth-2 loop (43us, ~900 TF ceiling of the
// 2-barrier structure); rec = v7 distance-3/depth-4 (4 LDS bufs, vmcnt(6),
// 4-deep B register rotation); gates0 t=0 path; two-table wprep; fp32 hs.
#define HW      256
#define COUT    1024
#define TSTEPS  8
#define BN_EPS  1e-3f
#define KTOT    2304

typedef unsigned short u16;
typedef unsigned int   u32;
typedef __attribute__((ext_vector_type(8))) _Float16 v8h;  // 8 x fp16
typedef __attribute__((ext_vector_type(4))) float v4f;

__device__ __forceinline__ u16 f2h(float x) {
    _Float16 h = (_Float16)x; return *(u16*)&h;
}
__device__ __forceinline__ float h2f(u16 u) {
    _Float16 h = *(_Float16*)&u; return (float)h;
}
__device__ __forceinline__ float hsig(float x) {
    return fminf(fmaxf(0.2f * x + 0.5f, 0.f), 1.f);
}

typedef __attribute__((address_space(1))) const unsigned int gas_u32;
typedef __attribute__((address_space(3))) unsigned int las_u32;
__device__ __forceinline__ void gl16(const void* g, void* l) {
    __builtin_amdgcn_global_load_lds((gas_u32*)g, (las_u32*)l, 16, 0, 0);
}

// ---------------------------------------------------------------------------
// Big input conv: M=8192, N'=1024, BM=BN=128, BK=64, 4 waves (2x2),
// r6 single-barrier depth-2 pipeline, slot-swizzled LDS, 2 blk/CU.
// ---------------------------------------------------------------------------
__global__ __launch_bounds__(256, 2) void conv_big_k(
    const u16* __restrict__ apad,     // (32,18,18,256) fp16 zero-padded
    const u16* __restrict__ wT,       // (1024 n', 2304) fp16
    const float* __restrict__ bias,   // (1024) original n order
    u16* __restrict__ out)            // (8192, 1024) fp16, n' order
{
    constexpr int KQ = 36;
    __shared__ u16 lds[2 * 16384];

    const int bid = blockIdx.x;
    const int xcd = bid & 7, idx = bid >> 3;
    const int by = (xcd >> 1) * 2 + (idx & 1);
    const int bx = (xcd & 1) * 32 + (idx >> 1);
    const int m0 = bx * 128, n0 = by * 128;
    const int tid = threadIdx.x, lane = tid & 63, w = tid >> 6;
    const int wr = w >> 1, wc = w & 1;
    const int lr = lane >> 3;
    const int g  = (lane & 7) ^ lr;
    const int fr = lane & 15, kc = lane >> 4;

    const char* a_src[4];
    #pragma unroll
    for (int i = 0; i < 4; ++i) {
        int m = m0 + w * 32 + i * 8 + lr;
        int img = m >> 8, pix = m & 255, yy = pix >> 4, xx = pix & 15;
        a_src[i] = (const char*)apad + ((((long)img * 18 + yy) * 18 + xx) * 256 + g * 8) * 2;
    }
    const char* b_src[4];
    #pragma unroll
    for (int i = 0; i < 4; ++i) {
        int n = n0 + w * 32 + i * 8 + lr;
        b_src[i] = (const char*)wT + ((long)n * KTOT + g * 8) * 2;
    }

    int aro[4][2], bro[4][2];
    #pragma unroll
    for (int mi = 0; mi < 4; ++mi) {
        int rl = wr * 64 + mi * 16 + fr;
        #pragma unroll
        for (int ks = 0; ks < 2; ++ks)
            aro[mi][ks] = rl * 128 + ((((ks << 2) | kc) ^ (fr & 7)) << 4);
    }
    #pragma unroll
    for (int ni = 0; ni < 4; ++ni) {
        int nr = wc * 64 + ni * 16 + fr;
        #pragma unroll
        for (int ks = 0; ks < 2; ++ks)
            bro[ni][ks] = 16384 + nr * 128 + ((((ks << 2) | kc) ^ (fr & 7)) << 4);
    }

    v4f acc[4][4];
    #pragma unroll
    for (int mi = 0; mi < 4; ++mi)
        #pragma unroll
        for (int ni = 0; ni < 4; ++ni) acc[mi][ni] = (v4f)0.f;

#define STAGE_B(J) { int j_ = (J); int dxy = j_ >> 2, c64 = j_ & 3;           \
    int dy = (dxy * 11) >> 5; int dx = dxy - dy * 3;                          \
    int aoff = ((dy * 18 + dx) * 256 + c64 * 64) * 2; int boff = j_ * 128;    \
    char* base = (char*)lds + (j_ & 1) * 32768;                               \
    _Pragma("unroll") for (int i = 0; i < 4; ++i)                             \
        gl16(a_src[i] + aoff, base + (w * 32 + i * 8) * 128);                 \
    _Pragma("unroll") for (int i = 0; i < 4; ++i)                             \
        gl16(b_src[i] + boff, base + 16384 + (w * 32 + i * 8) * 128); }

#define COMPUTE_B(J) { const char* base = (const char*)lds + ((J) & 1) * 32768; \
    v8h af[4][2], bf[4][2];                                                   \
    _Pragma("unroll") for (int mi = 0; mi < 4; ++mi)                          \
        _Pragma("unroll") for (int ks = 0; ks < 2; ++ks)                      \
            af[mi][ks] = *(const v8h*)(base + aro[mi][ks]);                   \
    _Pragma("unroll") for (int ni = 0; ni < 4; ++ni)                          \
        _Pragma("unroll") for (int ks = 0; ks < 2; ++ks)                      \
            bf[ni][ks] = *(const v8h*)(base + bro[ni][ks]);                   \
    __builtin_amdgcn_s_setprio(1);                                            \
    _Pragma("unroll") for (int ks = 0; ks < 2; ++ks)                          \
    _Pragma("unroll") for (int mi = 0; mi < 4; ++mi)                          \
    _Pragma("unroll") for (int ni = 0; ni < 4; ++ni)                          \
        acc[mi][ni] = __builtin_amdgcn_mfma_f32_16x16x32_f16(af[mi][ks], bf[ni][ks], acc[mi][ni], 0, 0, 0); \
    __builtin_amdgcn_s_setprio(0); }

    STAGE_B(0);
    for (int kq = 0; kq < KQ - 1; ++kq) {
        asm volatile("s_waitcnt vmcnt(0)" ::: "memory");
        __builtin_amdgcn_s_barrier();
        __builtin_amdgcn_sched_barrier(0);
        STAGE_B(kq + 1);
        COMPUTE_B(kq);
    }
    asm volatile("s_waitcnt vmcnt(0)" ::: "memory");
    __builtin_amdgcn_s_barrier();
    __builtin_amdgcn_sched_barrier(0);
    COMPUTE_B(KQ - 1);
#undef STAGE_B
#undef COMPUTE_B

    #pragma unroll
    for (int mi = 0; mi < 4; ++mi) {
        #pragma unroll
        for (int ni = 0; ni < 4; ++ni) {
            int mrow = m0 + wr * 64 + mi * 16 + ((lane >> 4) << 2);
            int ncol = n0 + wc * 64 + ni * 16 + fr;
            float b0 = bias[(ncol & 3) * 256 + (ncol >> 2)];
            #pragma unroll
            for (int r = 0; r < 4; ++r)
                out[(long)(mrow + r) * COUT + ncol] = f2h(acc[mi][ni][r] + b0);
        }
    }
}

// ---------------------------------------------------------------------------
// Recurrent conv + fused LSTM cell, v7 (r11 best): 64x64 tile, 256 blocks
// (1/CU), 8 waves (512 thr, 2m x 4n), wave 32m x 16n. Distance-3/depth-4
// pipeline: 4 LDS A-buffers, 4-deep B register rotation, uniform vmcnt(6).
// ---------------------------------------------------------------------------
__global__ __launch_bounds__(512) void rec_fused_k(
    const u16* __restrict__ ph_in,    // (4,18,18,256) fp16  h_{t-1}
    const u16* __restrict__ wTf,      // frag-packed Wh: (64 nf, 72 k32, 512)
    const u16* __restrict__ xg,       // (8192, 1024) fp16, n' order (incl bias)
    float* __restrict__ cbuf,         // (4,256,256)
    float* __restrict__ hs,           // (4,8,256,256)
    u16* __restrict__ ph_out,         // (4,18,18,256) fp16  h_t
    int t)
{
    __shared__ u16 lds[4 * 4096];     // 4 bufs x 8KB (A only)

    const int bid = blockIdx.x;       // 256: by-pairs per XCD (bijective)
    const int by = (bid & 7) * 2 + ((bid >> 3) & 1);   // 0..15
    const int bx = bid >> 4;                           // 0..15
    const int m0 = bx * 64, n0 = by * 64;
    const int tid = threadIdx.x, lane = tid & 63, w = tid >> 6;
    const int wr = w >> 2, wc = w & 3;
    const int fr = lane & 15, kc = lane >> 4;

    // A staging: thread stages row rt = tid>>3 (0..63), slot lane&7
    const char* a_src;
    {
        int rt = tid >> 3;
        int gg = (tid & 7) ^ (rt & 7);     // inverse swizzle on SOURCE granule
        int m = m0 + rt;
        int img = m >> 8, pix = m & 255, yy = pix >> 4, xx = pix & 15;
        a_src = (const char*)ph_in + ((((long)img * 18 + yy) * 18 + xx) * 256 + gg * 8) * 2;
    }
    // B fragment base: wave-col owns nf = by*4 + wc
    const char* b_base = (const char*)wTf + ((long)(by * 4 + wc) * 72) * 1024 + lane * 16;

    // A frag read offsets (swizzled slot), rows wr*32 + mi*16 + fr
    int aro[2][2];
    #pragma unroll
    for (int mi = 0; mi < 2; ++mi)
        #pragma unroll
        for (int ks = 0; ks < 2; ++ks)
            aro[mi][ks] = (wr * 32 + mi * 16 + fr) * 128 + ((((ks << 2) | kc) ^ (fr & 7)) << 4);

    v4f acc0 = (v4f)0.f, acc1 = (v4f)0.f;

#define STAGE_A(J) { int j_ = (J); int dxy = j_ >> 2, c64 = j_ & 3;           \
    int dy = (dxy * 11) >> 5; int dx = dxy - dy * 3;                          \
    int aoff = ((dy * 18 + dx) * 256 + c64 * 64) * 2;                         \
    gl16(a_src + aoff, (char*)lds + (j_ & 3) * 8192 + w * 1024); }

#define LDB(J, R0, R1) { R0 = *(const v8h*)(b_base + (2 * (J)) * 1024);       \
                         R1 = *(const v8h*)(b_base + (2 * (J) + 1) * 1024); }

#define BODY(KQ, C0, C1, L0, L1) {                                            \
    int kq_ = (KQ); int jj_ = kq_ + 3 < 36 ? kq_ + 3 : 35;                    \
    asm volatile("s_waitcnt vmcnt(6)" ::: "memory");                          \
    __builtin_amdgcn_s_barrier();                                             \
    __builtin_amdgcn_sched_barrier(0);                                        \
    LDB(jj_, L0, L1);                                                         \
    STAGE_A(jj_);                                                             \
    const char* base_ = (const char*)lds + (kq_ & 3) * 8192;                  \
    v8h af00_ = *(const v8h*)(base_ + aro[0][0]);                             \
    v8h af10_ = *(const v8h*)(base_ + aro[1][0]);                             \
    v8h af01_ = *(const v8h*)(base_ + aro[0][1]);                             \
    v8h af11_ = *(const v8h*)(base_ + aro[1][1]);                             \
    __builtin_amdgcn_s_setprio(1);                                            \
    acc0 = __builtin_amdgcn_mfma_f32_16x16x32_f16(af00_, C0, acc0, 0, 0, 0);  \
    acc1 = __builtin_amdgcn_mfma_f32_16x16x32_f16(af10_, C0, acc1, 0, 0, 0);  \
    acc0 = __builtin_amdgcn_mfma_f32_16x16x32_f16(af01_, C1, acc0, 0, 0, 0);  \
    acc1 = __builtin_amdgcn_mfma_f32_16x16x32_f16(af11_, C1, acc1, 0, 0, 0);  \
    __builtin_amdgcn_s_setprio(0); }

    v8h S00, S01, S10, S11, S20, S21, S30, S31;
    LDB(0, S00, S01); STAGE_A(0);
    LDB(1, S10, S11); STAGE_A(1);
    LDB(2, S20, S21); STAGE_A(2);
    for (int j = 0; j < 9; ++j) {
        int k0 = 4 * j;
        BODY(k0,     S00, S01, S30, S31);
        BODY(k0 + 1, S10, S11, S00, S01);
        BODY(k0 + 2, S20, S21, S10, S11);
        BODY(k0 + 3, S30, S31, S20, S21);
    }
#undef STAGE_A
#undef LDB
#undef BODY

    // epilogue: quad-transpose (gate-lane <-> row-reg), + xg(fp16), cell update.
    v4f accA[2] = {acc0, acc1};
    const bool gl0 = lane & 1, gl1 = lane & 2;
    #pragma unroll
    for (int mi = 0; mi < 2; ++mi) {
        float V0 = accA[mi][0], V1 = accA[mi][1];
        float V2 = accA[mi][2], V3 = accA[mi][3];
        float x0 = __shfl_xor(V0, 1), x1 = __shfl_xor(V1, 1);
        float x2 = __shfl_xor(V2, 1), x3 = __shfl_xor(V3, 1);
        float a0 = gl0 ? x1 : V0;
        float a1 = gl0 ? V1 : x0;
        float a2 = gl0 ? x3 : V2;
        float a3 = gl0 ? V3 : x2;
        float s0 = __shfl_xor(a0, 2), s1 = __shfl_xor(a1, 2);
        float s2 = __shfl_xor(a2, 2), s3 = __shfl_xor(a3, 2);
        float Ti = gl1 ? s2 : a0;
        float Tf = gl1 ? s3 : a1;
        float Tc = gl1 ? a2 : s0;
        float To = gl1 ? a3 : s1;

        int row = m0 + wr * 32 + mi * 16 + ((lane >> 4) << 2) + (lane & 3);
        int f4  = n0 + wc * 16 + (lane & 12);
        int img = row >> 8, pix = row & 255, fch = f4 >> 2;
        long xrow = ((long)(img * TSTEPS + t) * HW + pix);
        uint2 xb = *(const uint2*)&xg[xrow * COUT + f4];
        float pi = Ti + h2f((u16)(xb.x & 0xffff));
        float pf = Tf + h2f((u16)(xb.x >> 16));
        float pc = Tc + h2f((u16)(xb.y & 0xffff));
        float po = To + h2f((u16)(xb.y >> 16));
        long cidx = (long)row * 256 + fch;
        float c = hsig(pf) * cbuf[cidx] + hsig(pi) * tanhf(pc);
        float h = hsig(po) * tanhf(c);
        cbuf[cidx] = c;
        hs[xrow * 256 + fch] = h;
        int yy = pix >> 4, xx = pix & 15;
        ph_out[(((long)img * 18 + yy + 1) * 18 + xx + 1) * 256 + fch] = f2h(h);
    }
}

// ---------------------------------------------------------------------------
// t=0 cell: h0=0 -> gates = xg only (no conv). Writes cbuf/hs/ph_out.
// ---------------------------------------------------------------------------
__global__ __launch_bounds__(256) void gates0_k(
    const u16* __restrict__ xg, float* __restrict__ cbuf,
    float* __restrict__ hs, u16* __restrict__ ph_out)
{
    int idx = blockIdx.x * 256 + threadIdx.x;     // 0..262143
    int fch = idx & 255, row = idx >> 8;
    int img = row >> 8, pix = row & 255;
    long xrow = (long)(img * TSTEPS) * HW + pix;
    uint2 xb = *(const uint2*)&xg[xrow * COUT + fch * 4];
    float pi = h2f((u16)(xb.x & 0xffff));
    float pc = h2f((u16)(xb.y & 0xffff));
    float po = h2f((u16)(xb.y >> 16));
    float c = hsig(pi) * tanhf(pc);
    float h = hsig(po) * tanhf(c);
    cbuf[(long)row * 256 + fch] = c;
    hs[xrow * 256 + fch] = h;
    int yy = pix >> 4, xx = pix & 15;
    ph_out[(((long)img * 18 + yy + 1) * 18 + xx + 1) * 256 + fch] = f2h(h);
}

// ---------------------------------------------------------------------------
// weight preps
// ---------------------------------------------------------------------------
__global__ __launch_bounds__(256) void wprep_k(const float* __restrict__ w,
                                               u16* __restrict__ wT)
{
    int k0 = blockIdx.x * 32;
    int np = blockIdx.y * 256 + threadIdx.x;      // n' row
    int n  = (np & 3) * 256 + (np >> 2);
    u32 pk[16];
    #pragma unroll
    for (int kk = 0; kk < 32; kk += 2) {
        float a = w[(long)(k0 + kk) * COUT + n];
        float b = w[(long)(k0 + kk + 1) * COUT + n];
        pk[kk >> 1] = (u32)f2h(a) | ((u32)f2h(b) << 16);
    }
    uint4* dst = (uint4*)&wT[(long)np * KTOT + k0];
    dst[0] = make_uint4(pk[0], pk[1], pk[2], pk[3]);
    dst[1] = make_uint4(pk[4], pk[5], pk[6], pk[7]);
    dst[2] = make_uint4(pk[8], pk[9], pk[10], pk[11]);
    dst[3] = make_uint4(pk[12], pk[13], pk[14], pk[15]);
}

// fragment-packed prep: wTf[((nf*72)+k32)*512 + l*8 + e] = Wh[k][n]
__global__ __launch_bounds__(256) void wprep_frag_k(const float* __restrict__ w,
                                                    u16* __restrict__ wTf)
{
    int kq = blockIdx.x;                       // 0..71
    int nf = blockIdx.y * 4 + (threadIdx.x >> 6);
    int l  = threadIdx.x & 63;
    int np = nf * 16 + (l & 15);
    int n  = (np & 3) * 256 + (np >> 2);
    int k0 = kq * 32 + (l >> 4) * 8;
    u32 pk[4];
    #pragma unroll
    for (int e = 0; e < 8; e += 2) {
        float a = w[(long)(k0 + e) * COUT + n];
        float b = w[(long)(k0 + e + 1) * COUT + n];
        pk[e >> 1] = (u32)f2h(a) | ((u32)f2h(b) << 16);
    }
    *(uint4*)&wTf[((long)(nf * 72) + kq) * 512 + l * 8] =
        make_uint4(pk[0], pk[1], pk[2], pk[3]);
}

// ---------------------------------------------------------------------------
// convert input x (32,16,16,256) fp32 -> pad_x interior fp16
// ---------------------------------------------------------------------------
__global__ __launch_bounds__(256) void convert_x_k(const float* __restrict__ x,
                                                   u16* __restrict__ padx)
{
    int q = blockIdx.x * 256 + threadIdx.x;
    int e0 = q * 4;
    int f = e0 & 255, pix = (e0 >> 8) & 255, img = e0 >> 16;
    float4 v = ((const float4*)x)[q];
    int yy = pix >> 4, xx = pix & 15;
    long o = (((long)img * 18 + yy + 1) * 18 + xx + 1) * 256 + f;
    u32 lo = (u32)f2h(v.x) | ((u32)f2h(v.y) << 16);
    u32 hi = (u32)f2h(v.z) | ((u32)f2h(v.w) << 16);
    *(uint2*)&padx[o] = make_uint2(lo, hi);
}

// ---------------------------------------------------------------------------
// BatchNorm: deterministic two-stage stats + apply
// ---------------------------------------------------------------------------
__global__ __launch_bounds__(256) void bn_stats1_k(
    const float* __restrict__ x, float* __restrict__ partial)
{
    const int tid = threadIdx.x;
    const int blk = blockIdx.x;                // 64 blocks
    float s = 0.f, s2 = 0.f;
    const long base = (long)blk * 128 * 256;
    #pragma unroll 8
    for (int gi = 0; gi < 128; ++gi) {
        float v = x[base + gi * 256 + tid];
        s += v; s2 += v * v;
    }
    partial[blk * 512 + tid]       = s;
    partial[blk * 512 + 256 + tid] = s2;
}

__global__ __launch_bounds__(256) void bn_stats2_k(
    const float* __restrict__ partial, const float* __restrict__ gamma,
    const float* __restrict__ beta, float* __restrict__ stats)
{
    const int f = threadIdx.x;
    float s = 0.f, s2 = 0.f;
    #pragma unroll 8
    for (int b = 0; b < 64; ++b) {
        s  += partial[b * 512 + f];
        s2 += partial[b * 512 + 256 + f];
    }
    const float inv_n = 1.f / 8192.f;
    float mu  = s * inv_n;
    float var = s2 * inv_n - mu * mu;
    float sc  = gamma[f] * rsqrtf(var + BN_EPS);
    stats[f]       = sc;
    stats[256 + f] = beta[f] - mu * sc;
}

__global__ __launch_bounds__(256) void bn_apply_k(
    const float* __restrict__ x, const float* __restrict__ stats,
    u16* __restrict__ padx, float* __restrict__ out)
{
    const int q = blockIdx.x * 256 + threadIdx.x;
    const int e0 = q * 4;
    const int f = e0 & 255, pix = (e0 >> 8) & 255, img = e0 >> 16;
    float4 v  = ((const float4*)x)[q];
    float4 sc = *(const float4*)(stats + f);
    float4 sh = *(const float4*)(stats + 256 + f);
    v.x = v.x * sc.x + sh.x;
    v.y = v.y * sc.y + sh.y;
    v.z = v.z * sc.z + sh.z;
    v.w = v.w * sc.w + sh.w;
    if (out) ((float4*)out)[q] = v;
    if (padx) {
        int yy = pix >> 4, xx = pix & 15;
        long o = (((long)img * 18 + yy + 1) * 18 + xx + 1) * 256 + f;
        u32 lo = (u32)f2h(v.x) | ((u32)f2h(v.y) << 16);
        u32 hi = (u32)f2h(v.z) | ((u32)f2h(v.w) << 16);
        *(uint2*)&padx[o] = make_uint2(lo, hi);
    }
}

// ---------------------------------------------------------------------------
extern "C" void kernel_launch(void* const* d_in, const int* in_sizes, int n_in,
                              void* d_out, int out_size, void* d_ws, size_t ws_size,
                              hipStream_t stream)
{
    const float* x0    = (const float*)d_in[0];
    const float* Wx[3] = {(const float*)d_in[1], (const float*)d_in[6],  (const float*)d_in[11]};
    const float* Wh[3] = {(const float*)d_in[2], (const float*)d_in[7],  (const float*)d_in[12]};
    const float* bb[3] = {(const float*)d_in[3], (const float*)d_in[8],  (const float*)d_in[13]};
    const float* gg[3] = {(const float*)d_in[4], (const float*)d_in[9],  (const float*)d_in[14]};
    const float* be[3] = {(const float*)d_in[5], (const float*)d_in[10], (const float*)d_in[15]};

    float* ws    = (float*)d_ws;
    u16*  xg     = (u16*)ws;              // 8,388,608 u16 (8192 x 1024 fp16, n')
    float* cbuf  = ws   + 4194304;        //   262,144 f32
    float* hs    = cbuf + 262144;         // 2,097,152 f32
    float* part  = hs   + 2097152;        //    32,768 (64 x 512)
    float* stats = part + 262144;         //       512
    u16*  pad_x  = (u16*)(stats + 512);   // 32*18*18*256 fp16
    u16*  pad_h  = pad_x + 2654208;       // 2 x 331,776 (ping-pong)
    u16*  wTx    = pad_h + 663552;        // 1024*2304 (row-major, conv_big)
    u16*  wTf    = wTx   + 2359296;       // 64*72*512 (frag-packed, rec)
    const long PHN = 331776;

    hipMemsetAsync(pad_x, 0, 2654208 * sizeof(u16), stream);   // halos
    hipMemsetAsync(pad_h, 0, 2 * PHN * sizeof(u16), stream);   // halos (once)
    hipLaunchKernelGGL(convert_x_k, dim3(2048), dim3(256), 0, stream, x0, pad_x);

    for (int l = 0; l < 3; ++l) {
        hipLaunchKernelGGL(wprep_k, dim3(72, 4), dim3(256), 0, stream, Wx[l], wTx);
        hipLaunchKernelGGL(wprep_frag_k, dim3(72, 16), dim3(256), 0, stream, Wh[l], wTf);

        hipLaunchKernelGGL(conv_big_k, dim3(512), dim3(256), 0, stream,
            pad_x, wTx, bb[l], xg);

        // t = 0: gates-only (h0 = 0); writes ph buffer 1
        hipLaunchKernelGGL(gates0_k, dim3(1024), dim3(256), 0, stream,
            xg, cbuf, hs, pad_h + PHN);

        for (int t = 1; t < TSTEPS; ++t) {
            hipLaunchKernelGGL(rec_fused_k, dim3(256), dim3(512), 0, stream,
                pad_h + (t & 1) * PHN, wTf, xg, cbuf, hs,
                pad_h + ((t & 1) ^ 1) * PHN, t);
        }

        hipLaunchKernelGGL(bn_stats1_k, dim3(64), dim3(256), 0, stream, hs, part);
        hipLaunchKernelGGL(bn_stats2_k, dim3(1), dim3(256), 0, stream, part, gg[l], be[l], stats);
        hipLaunchKernelGGL(bn_apply_k, dim3(2048), dim3(256), 0, stream, hs, stats,
            (l < 2) ? pad_x : (u16*)nullptr, (l == 2) ? (float*)d_out : (float*)nullptr);
    }
}